// Round 7
// baseline (288.503 us; speedup 1.0000x reference)
//
#include <hip/hip_runtime.h>
#include <hip/hip_cooperative_groups.h>

namespace cg = cooperative_groups;

// Problem dims (fixed by the reference)
#define BB 2
#define LL 1024
#define DI 1536
#define DS 16
#define TPB 256
#define NC 64
#define CL (LL / NC)                      // 16
#define NDBLK (DI / TPB)                  // 6
#define NBLK (NC * NDBLK * BB)            // 768 blocks = 3 per CU
#define SCAN_BLKS ((BB * DI * DS) / TPB)  // 192

#define LOG2E 1.44269504088896340736f

__device__ __forceinline__ float exp2_fast(float x) { return __builtin_amdgcn_exp2f(x); }

// ---------------------------------------------------------------------------
// Fused cooperative selective scan:
//  Phase A: per-block chunk aggregates (sdt, Bacc[16]); dt/uu kept in regs.
//  grid.sync()
//  Phase B: 192 blocks scan chunk prefixes per (b,d,n) chain -> xin.
//  grid.sync()
//  Phase C: y-walk reusing registered dt/uu (u/delta read ONCE total).
// Layouts (d-minor, all coalesced):
//  sdtw [c][b][d], bsumw/xinw [c][b][n][d]
// ---------------------------------------------------------------------------
__global__ __launch_bounds__(TPB, 3) void ss_coop(
    const float* __restrict__ u, const float* __restrict__ delta,
    const float* __restrict__ A, const float* __restrict__ Bm,
    const float* __restrict__ Cm, const float* __restrict__ Dv,
    float* __restrict__ sdtw, float* __restrict__ bsumw,
    float* __restrict__ xinw, float* __restrict__ y)
{
    const int bx   = blockIdx.x;
    const int c    = bx % NC;
    const int t2   = bx / NC;
    const int dblk = t2 % NDBLK;
    const int b    = t2 / NDBLK;
    const int tid  = threadIdx.x;
    const int d    = dblk * TPB + tid;

    float Av2[DS];
    {
        const float4* Ap = (const float4*)(A + (size_t)d * DS);
        #pragma unroll
        for (int q = 0; q < 4; ++q) {
            const float4 av = Ap[q];
            Av2[q*4+0] = av.x * LOG2E; Av2[q*4+1] = av.y * LOG2E;
            Av2[q*4+2] = av.z * LOG2E; Av2[q*4+3] = av.w * LOG2E;
        }
    }

    const size_t bl0 = (size_t)b * LL + (size_t)c * CL;
    const float* __restrict__ dp = delta + bl0 * DI + d;
    const float* __restrict__ up = u     + bl0 * DI + d;
    const float* __restrict__ bp = Bm    + bl0 * DS;   // wave-uniform -> s_load

    // Burst-load chunk's dt/uu; live in registers through all three phases.
    float dt[CL], uu[CL];
    #pragma unroll
    for (int i = 0; i < CL; ++i) {
        dt[i] = dp[(size_t)i * DI];     // coalesced 256B/wave
        uu[i] = up[(size_t)i * DI];
    }

    // ---- Phase A: chunk-local aggregate ----
    float Bacc[DS];
    #pragma unroll
    for (int n = 0; n < DS; ++n) Bacc[n] = 0.0f;
    float sdt = 0.0f;
    #pragma unroll
    for (int i = 0; i < CL; ++i) {
        const float du = dt[i] * uu[i];
        sdt += dt[i];
        const float* __restrict__ bt = bp + i * DS;
        #pragma unroll
        for (int n = 0; n < DS; ++n) {
            const float a = exp2_fast(dt[i] * Av2[n]);
            Bacc[n] = fmaf(a, Bacc[n], du * bt[n]);
        }
    }

    sdtw[((size_t)c * BB + b) * DI + d] = sdt;
    {
        float* __restrict__ bw = bsumw + (size_t)(c * BB + b) * DS * DI + d;
        #pragma unroll
        for (int n = 0; n < DS; ++n) bw[(size_t)n * DI] = Bacc[n];
    }

    cg::this_grid().sync();

    // ---- Phase B: chunk-prefix exclusive scan (192 of 768 blocks) ----
    if (bx < SCAN_BLKS) {
        const int gid = bx * TPB + tid;     // (b2*DS+n2)*DI + d2
        const int d2  = gid % DI;
        const int bn  = gid / DI;
        const int n2  = bn & (DS - 1);
        const int b2  = bn >> 4;
        const float Av2s = A[d2 * DS + n2] * LOG2E;
        const size_t cstr = (size_t)BB * DS * DI;
        const size_t sstr = (size_t)BB * DI;
        const size_t soff = (size_t)b2 * DI + d2;
        float x = 0.0f;
        #pragma unroll 4
        for (int cc = 0; cc < NC; ++cc) {
            xinw[(size_t)cc * cstr + gid] = x;           // state BEFORE chunk cc
            const float a = exp2_fast(Av2s * sdtw[(size_t)cc * sstr + soff]);
            x = fmaf(a, x, bsumw[(size_t)cc * cstr + gid]);
        }
    }

    cg::this_grid().sync();

    // ---- Phase C: y-walk (dt/uu still in registers) ----
    float x[DS];
    {
        const float* __restrict__ xp = xinw + (size_t)(c * BB + b) * DS * DI + d;
        #pragma unroll
        for (int n = 0; n < DS; ++n) x[n] = xp[(size_t)n * DI];  // coalesced per n
    }
    const float Dd = Dv[d];
    const float* __restrict__ cp = Cm + bl0 * DS;   // wave-uniform
    float* __restrict__ yp       = y  + bl0 * DI + d;

    #pragma unroll
    for (int i = 0; i < CL; ++i) {
        const float du = dt[i] * uu[i];
        const float* __restrict__ bt = bp + i * DS;
        const float* __restrict__ ct = cp + i * DS;
        float y0 = 0.0f, y1 = 0.0f;
        #pragma unroll
        for (int n = 0; n < DS; ++n) {
            const float a = exp2_fast(dt[i] * Av2[n]);
            x[n] = fmaf(a, x[n], du * bt[n]);
            if (n & 1) y1 = fmaf(x[n], ct[n], y1);
            else       y0 = fmaf(x[n], ct[n], y0);
        }
        yp[(size_t)i * DI] = fmaf(uu[i], Dd, y0 + y1);
    }
}

// ---------------------------------------------------------------------------
// Fallback: proven round-3 three-kernel path (NC=64)
// ---------------------------------------------------------------------------
template <int NCc>
__global__ __launch_bounds__(TPB) void ss1(
    const float* __restrict__ u, const float* __restrict__ delta,
    const float* __restrict__ A, const float* __restrict__ Bm,
    float* __restrict__ sdt_out, float* __restrict__ bsum)
{
    constexpr int CLc = LL / NCc;
    const int d = blockIdx.x * TPB + threadIdx.x;
    const int c = blockIdx.y;
    const int b = blockIdx.z;

    float Av2[DS];
    const float4* Ap = (const float4*)(A + (size_t)d * DS);
    #pragma unroll
    for (int q = 0; q < 4; ++q) {
        const float4 av = Ap[q];
        Av2[q*4+0] = av.x * LOG2E; Av2[q*4+1] = av.y * LOG2E;
        Av2[q*4+2] = av.z * LOG2E; Av2[q*4+3] = av.w * LOG2E;
    }

    const size_t bl0 = (size_t)b * LL + (size_t)c * CLc;
    const float* __restrict__ dp = delta + bl0 * DI + d;
    const float* __restrict__ up = u     + bl0 * DI + d;
    const float* __restrict__ bp = Bm    + bl0 * DS;

    float dt[CLc], uu[CLc];
    #pragma unroll
    for (int i = 0; i < CLc; ++i) {
        dt[i] = dp[(size_t)i * DI];
        uu[i] = up[(size_t)i * DI];
    }

    float Bacc[DS];
    #pragma unroll
    for (int n = 0; n < DS; ++n) Bacc[n] = 0.0f;
    float sdt = 0.0f;

    #pragma unroll
    for (int i = 0; i < CLc; ++i) {
        const float du = dt[i] * uu[i];
        sdt += dt[i];
        const float* __restrict__ bt = bp + i * DS;
        #pragma unroll
        for (int n = 0; n < DS; ++n) {
            const float a = exp2_fast(dt[i] * Av2[n]);
            Bacc[n] = fmaf(a, Bacc[n], du * bt[n]);
        }
    }

    sdt_out[((size_t)c * BB + b) * DI + d] = sdt;
    float* __restrict__ sp = bsum + (size_t)(c * BB + b) * DS * DI + d;
    #pragma unroll
    for (int n = 0; n < DS; ++n) sp[(size_t)n * DI] = Bacc[n];
}

template <int NCc>
__global__ __launch_bounds__(TPB) void ss_scan(
    const float* __restrict__ A,
    const float* __restrict__ sdt_in, const float* __restrict__ bsum,
    float* __restrict__ xin)
{
    const int gid = blockIdx.x * TPB + threadIdx.x;
    const int d   = gid % DI;
    const int bn  = gid / DI;
    const int n   = bn & 15;
    const float Av2 = A[d * DS + n] * LOG2E;

    const size_t cstr = (size_t)BB * DS * DI;
    const size_t sstr = (size_t)BB * DI;
    const size_t soff = (size_t)(bn >> 4) * DI + d;

    float x = 0.0f;
    #pragma unroll 4
    for (int c = 0; c < NCc; ++c) {
        xin[(size_t)c * cstr + gid] = x;
        const float a = exp2_fast(Av2 * sdt_in[(size_t)c * sstr + soff]);
        x = fmaf(a, x, bsum[(size_t)c * cstr + gid]);
    }
}

template <int NCc>
__global__ __launch_bounds__(TPB) void ss2(
    const float* __restrict__ u, const float* __restrict__ delta,
    const float* __restrict__ A, const float* __restrict__ Bm,
    const float* __restrict__ Cm, const float* __restrict__ Dv,
    const float* __restrict__ xin, float* __restrict__ y)
{
    constexpr int CLc = LL / NCc;
    const int d = blockIdx.x * TPB + threadIdx.x;
    const int c = blockIdx.y;
    const int b = blockIdx.z;

    float Av2[DS];
    const float4* Ap = (const float4*)(A + (size_t)d * DS);
    #pragma unroll
    for (int q = 0; q < 4; ++q) {
        const float4 av = Ap[q];
        Av2[q*4+0] = av.x * LOG2E; Av2[q*4+1] = av.y * LOG2E;
        Av2[q*4+2] = av.z * LOG2E; Av2[q*4+3] = av.w * LOG2E;
    }

    float x[DS];
    {
        const float* __restrict__ xp = xin + (size_t)(c * BB + b) * DS * DI + d;
        #pragma unroll
        for (int n = 0; n < DS; ++n) x[n] = xp[(size_t)n * DI];
    }

    const float Dd = Dv[d];
    const size_t bl0 = (size_t)b * LL + (size_t)c * CLc;
    const float* __restrict__ dp = delta + bl0 * DI + d;
    const float* __restrict__ up = u     + bl0 * DI + d;
    const float* __restrict__ bp = Bm    + bl0 * DS;
    const float* __restrict__ cp = Cm    + bl0 * DS;
    float* __restrict__ yp       = y     + bl0 * DI + d;

    float dt[CLc], uu[CLc];
    #pragma unroll
    for (int i = 0; i < CLc; ++i) {
        dt[i] = dp[(size_t)i * DI];
        uu[i] = up[(size_t)i * DI];
    }

    #pragma unroll
    for (int i = 0; i < CLc; ++i) {
        const float du = dt[i] * uu[i];
        const float* __restrict__ bt = bp + i * DS;
        const float* __restrict__ ct = cp + i * DS;
        float y0 = 0.0f, y1 = 0.0f;
        #pragma unroll
        for (int n = 0; n < DS; ++n) {
            const float a = exp2_fast(dt[i] * Av2[n]);
            x[n] = fmaf(a, x[n], du * bt[n]);
            if (n & 1) y1 = fmaf(x[n], ct[n], y1);
            else       y0 = fmaf(x[n], ct[n], y0);
        }
        yp[(size_t)i * DI] = fmaf(uu[i], Dd, y0 + y1);
    }
}

__global__ __launch_bounds__(TPB) void ss_serial(
    const float* __restrict__ u, const float* __restrict__ delta,
    const float* __restrict__ A, const float* __restrict__ Bm,
    const float* __restrict__ Cm, const float* __restrict__ Dv,
    float* __restrict__ y)
{
    const int d = blockIdx.x * TPB + threadIdx.x;
    const int b = blockIdx.z;

    float Av2[DS];
    #pragma unroll
    for (int n = 0; n < DS; ++n) Av2[n] = A[d * DS + n] * LOG2E;

    float x[DS];
    #pragma unroll
    for (int n = 0; n < DS; ++n) x[n] = 0.0f;

    const float Dd = Dv[d];
    const size_t bl0 = (size_t)b * LL;
    const float* __restrict__ dp = delta + bl0 * DI + d;
    const float* __restrict__ up = u     + bl0 * DI + d;
    const float* __restrict__ bp = Bm    + bl0 * DS;
    const float* __restrict__ cp = Cm    + bl0 * DS;
    float* __restrict__ yp       = y     + bl0 * DI + d;

    for (int t = 0; t < LL; ++t) {
        const float dtv = dp[(size_t)t * DI];
        const float uuv = up[(size_t)t * DI];
        const float du = dtv * uuv;
        const float* __restrict__ bt = bp + t * DS;
        const float* __restrict__ ct = cp + t * DS;
        float y0 = 0.0f, y1 = 0.0f;
        #pragma unroll
        for (int n = 0; n < DS; ++n) {
            const float a = exp2_fast(dtv * Av2[n]);
            x[n] = fmaf(a, x[n], du * bt[n]);
            if (n & 1) y1 = fmaf(x[n], ct[n], y1);
            else       y0 = fmaf(x[n], ct[n], y0);
        }
        yp[(size_t)t * DI] = fmaf(uuv, Dd, y0 + y1);
    }
}

static void launch_fallback(const float* u, const float* delta, const float* A,
                            const float* Bm, const float* Cm, const float* Dv,
                            float* y, void* d_ws, size_t ws_size, hipStream_t stream) {
    const size_t sdt_bytes  = (size_t)NC * BB * DI * sizeof(float);
    const size_t bsum_bytes = (size_t)NC * BB * DI * DS * sizeof(float);
    if (ws_size >= sdt_bytes + 2 * bsum_bytes) {
        float* sdt  = (float*)d_ws;
        float* bsum = (float*)((char*)d_ws + sdt_bytes);
        float* xin  = (float*)((char*)d_ws + sdt_bytes + bsum_bytes);
        dim3 grid1(DI / TPB, NC, BB);
        ss1<NC><<<grid1, TPB, 0, stream>>>(u, delta, A, Bm, sdt, bsum);
        dim3 gridS((BB * DI * DS) / TPB, 1, 1);
        ss_scan<NC><<<gridS, TPB, 0, stream>>>(A, sdt, bsum, xin);
        ss2<NC><<<grid1, TPB, 0, stream>>>(u, delta, A, Bm, Cm, Dv, xin, y);
    } else {
        dim3 grid(DI / TPB, 1, BB);
        ss_serial<<<grid, TPB, 0, stream>>>(u, delta, A, Bm, Cm, Dv, y);
    }
}

extern "C" void kernel_launch(void* const* d_in, const int* in_sizes, int n_in,
                              void* d_out, int out_size, void* d_ws, size_t ws_size,
                              hipStream_t stream) {
    const float* u     = (const float*)d_in[0];
    const float* delta = (const float*)d_in[1];
    const float* A     = (const float*)d_in[2];
    const float* Bm    = (const float*)d_in[3];
    const float* Cm    = (const float*)d_in[4];
    const float* Dv    = (const float*)d_in[5];
    float* y = (float*)d_out;

    const size_t sdt_bytes  = (size_t)NC * BB * DI * sizeof(float);        // 0.8 MB
    const size_t bsum_bytes = (size_t)NC * BB * DI * DS * sizeof(float);   // 12.6 MB
    const size_t coop_need  = sdt_bytes + 2 * bsum_bytes;                  // ~26 MB

    if (ws_size >= coop_need) {
        float* sdtw  = (float*)d_ws;
        float* bsumw = (float*)((char*)d_ws + sdt_bytes);
        float* xinw  = (float*)((char*)d_ws + sdt_bytes + bsum_bytes);

        void* args[] = {
            (void*)&u, (void*)&delta, (void*)&A, (void*)&Bm, (void*)&Cm,
            (void*)&Dv, (void*)&sdtw, (void*)&bsumw, (void*)&xinw, (void*)&y
        };
        hipError_t err = hipLaunchCooperativeKernel(
            (const void*)ss_coop, dim3(NBLK), dim3(TPB), args, 0, stream);
        if (err == hipSuccess) return;
        // fall through to non-cooperative path on failure
    }

    launch_fallback(u, delta, A, Bm, Cm, Dv, y, d_ws, ws_size, stream);
}

// Round 8
// 185.225 us; speedup vs baseline: 1.5576x; 1.5576x over previous
//
#include <hip/hip_runtime.h>

// Problem dims (fixed by the reference)
#define BB 2
#define LL 1024
#define DI 1536
#define DS 16

// Fused-block config
#define DT 8                 // d's per block
#define TPB 512              // 8 waves
#define SEGS 64              // segments per (b,d) chain (intra-block)
#define SL (LL / SEGS)       // 16 steps per segment
#define DSP (DS + 1)         // padded n-dim for LDS bank spread

#define LOG2E 1.44269504088896340736f

__device__ __forceinline__ float exp2_fast(float x) { return __builtin_amdgcn_exp2f(x); }

// ---------------------------------------------------------------------------
// Single-dispatch fused selective scan.
// Block <-> (b, 8-d tile). Thread <-> (d_local = tid&7, seg = tid>>3).
// Phase A: per-segment aggregates (sdt, Bacc[16]) -> LDS.
// Phase B: 128 threads scan 64 segments per (d,n) chain in LDS (exclusive).
// Phase C: y-walk; dt kept in registers, uu re-read (L2-hot).
// All cross-thread traffic stays in LDS; only 2 __syncthreads().
// ---------------------------------------------------------------------------
__global__ __launch_bounds__(TPB, 4) void ss_fused_lds(
    const float* __restrict__ u, const float* __restrict__ delta,
    const float* __restrict__ A, const float* __restrict__ Bm,
    const float* __restrict__ Cm, const float* __restrict__ Dv,
    float* __restrict__ y)
{
    __shared__ float sdt_l[SEGS][DT];        // 2 KB
    __shared__ float bagg[SEGS][DT][DSP];    // ~34 KB
    __shared__ float xin[SEGS][DT][DSP];     // ~34 KB

    const int tid = threadIdx.x;
    const int dl  = tid & (DT - 1);          // d within tile
    const int seg = tid >> 3;                // 0..63
    const int d0  = blockIdx.x * DT;
    const int b   = blockIdx.y;
    const int d   = d0 + dl;

    // A row for this d (16 floats, 64B-aligned), pre-scaled by log2(e)
    float Av2[DS];
    {
        const float4* Ap = (const float4*)(A + (size_t)d * DS);
        #pragma unroll
        for (int q = 0; q < 4; ++q) {
            const float4 av = Ap[q];
            Av2[q*4+0] = av.x * LOG2E; Av2[q*4+1] = av.y * LOG2E;
            Av2[q*4+2] = av.z * LOG2E; Av2[q*4+3] = av.w * LOG2E;
        }
    }

    const size_t rowbase = ((size_t)b * LL + (size_t)seg * SL);
    const float* __restrict__ dp = delta + rowbase * DI + d;
    const float* __restrict__ up = u     + rowbase * DI + d;
    const float* __restrict__ bp = Bm    + rowbase * DS;
    const float* __restrict__ cp = Cm    + rowbase * DS;

    // Segment's dt: burst-load, kept in registers through phase C.
    float dt[SL];
    #pragma unroll
    for (int i = 0; i < SL; ++i) dt[i] = dp[(size_t)i * DI];

    // ---- Phase A: segment-local aggregate ----
    float Bacc[DS];
    #pragma unroll
    for (int n = 0; n < DS; ++n) Bacc[n] = 0.0f;
    float sdt = 0.0f;

    #pragma unroll
    for (int i = 0; i < SL; ++i) {
        const float uu = up[(size_t)i * DI];
        const float du = dt[i] * uu;
        sdt += dt[i];
        // B row: 8 lanes (same seg) share the address -> merged/broadcast
        const float4* brow = (const float4*)(bp + (size_t)i * DS);
        const float4 b0 = brow[0], b1 = brow[1], b2 = brow[2], b3 = brow[3];
        const float bv[DS] = {b0.x,b0.y,b0.z,b0.w, b1.x,b1.y,b1.z,b1.w,
                              b2.x,b2.y,b2.z,b2.w, b3.x,b3.y,b3.z,b3.w};
        #pragma unroll
        for (int n = 0; n < DS; ++n) {
            const float a = exp2_fast(dt[i] * Av2[n]);
            Bacc[n] = fmaf(a, Bacc[n], du * bv[n]);
        }
    }

    sdt_l[seg][dl] = sdt;
    #pragma unroll
    for (int n = 0; n < DS; ++n) bagg[seg][dl][n] = Bacc[n];

    __syncthreads();

    // ---- Phase B: exclusive scan over segments per (d,n) chain ----
    if (tid < DT * DS) {                     // 128 scan threads
        const int sd = tid & (DT - 1);
        const int sn = tid >> 3;             // 0..15
        const float av2 = A[(size_t)(d0 + sd) * DS + sn] * LOG2E;
        float x = 0.0f;
        #pragma unroll 4
        for (int s = 0; s < SEGS; ++s) {
            xin[s][sd][sn] = x;              // state BEFORE segment s
            const float a = exp2_fast(av2 * sdt_l[s][sd]);
            x = fmaf(a, x, bagg[s][sd][sn]);
        }
    }

    __syncthreads();

    // ---- Phase C: y-walk (dt in regs; uu re-read, L2-hot) ----
    float x[DS];
    #pragma unroll
    for (int n = 0; n < DS; ++n) x[n] = xin[seg][dl][n];

    const float Dd = Dv[d];
    float* __restrict__ yp = y + rowbase * DI + d;

    #pragma unroll
    for (int i = 0; i < SL; ++i) {
        const float uu = up[(size_t)i * DI];
        const float du = dt[i] * uu;
        const float4* brow = (const float4*)(bp + (size_t)i * DS);
        const float4* crow = (const float4*)(cp + (size_t)i * DS);
        const float4 b0 = brow[0], b1 = brow[1], b2 = brow[2], b3 = brow[3];
        const float4 c0 = crow[0], c1 = crow[1], c2 = crow[2], c3 = crow[3];
        const float bv[DS] = {b0.x,b0.y,b0.z,b0.w, b1.x,b1.y,b1.z,b1.w,
                              b2.x,b2.y,b2.z,b2.w, b3.x,b3.y,b3.z,b3.w};
        const float cv[DS] = {c0.x,c0.y,c0.z,c0.w, c1.x,c1.y,c1.z,c1.w,
                              c2.x,c2.y,c2.z,c2.w, c3.x,c3.y,c3.z,c3.w};
        float y0 = 0.0f, y1 = 0.0f;
        #pragma unroll
        for (int n = 0; n < DS; ++n) {
            const float a = exp2_fast(dt[i] * Av2[n]);
            x[n] = fmaf(a, x[n], du * bv[n]);
            if (n & 1) y1 = fmaf(x[n], cv[n], y1);
            else       y0 = fmaf(x[n], cv[n], y0);
        }
        yp[(size_t)i * DI] = fmaf(uu, Dd, y0 + y1);
    }
}

extern "C" void kernel_launch(void* const* d_in, const int* in_sizes, int n_in,
                              void* d_out, int out_size, void* d_ws, size_t ws_size,
                              hipStream_t stream) {
    const float* u     = (const float*)d_in[0];
    const float* delta = (const float*)d_in[1];
    const float* A     = (const float*)d_in[2];
    const float* Bm    = (const float*)d_in[3];
    const float* Cm    = (const float*)d_in[4];
    const float* Dv    = (const float*)d_in[5];
    float* y = (float*)d_out;

    (void)d_ws; (void)ws_size;

    dim3 grid(DI / DT, BB);   // 192 x 2 = 384 blocks, 512 threads each
    ss_fused_lds<<<grid, TPB, 0, stream>>>(u, delta, A, Bm, Cm, Dv, y);
}

// Round 9
// 40.596 us; speedup vs baseline: 7.1068x; 4.5627x over previous
//
#include <hip/hip_runtime.h>

// Problem dims (fixed by the reference)
#define BB 2
#define LL 1024
#define DI 1536
#define DS 16
#define TPB 256

#define LOG2E 1.44269504088896340736f

__device__ __forceinline__ float exp2_fast(float x) { return __builtin_amdgcn_exp2f(x); }

// ---------------------------------------------------------------------------
// Pass 1: thread <-> (b, d, chunk); all 16 n-states in registers.
// B tile [CL][16] staged via LDS (one coalesced 1KB load), per-step access is
// an all-lanes-same-address ds_read broadcast (no per-step global loads).
// Stores per-chunk: sdt = sum(delta) and Bacc[n]:
//   x_after = exp2(Av2[n]*sdt)*x_before + Bacc[n]
// Layouts: sdt [c][b][d], bsum [c][b][d][n] (n-minor, as round 3)
// ---------------------------------------------------------------------------
template <int NCc>
__global__ __launch_bounds__(TPB) void ss1(
    const float* __restrict__ u, const float* __restrict__ delta,
    const float* __restrict__ A, const float* __restrict__ Bm,
    float* __restrict__ sdt_out, float* __restrict__ bsum)
{
    constexpr int CLc = LL / NCc;
    __shared__ float bsh[CLc * DS];          // 1 KB for CL=16

    const int tid = threadIdx.x;
    const int d = blockIdx.x * TPB + tid;
    const int c = blockIdx.y;
    const int b = blockIdx.z;

    const size_t bl0 = (size_t)b * LL + (size_t)c * CLc;

    // Stage B tile: CL*DS = 256 consecutive floats, one coalesced load.
    {
        const float* __restrict__ bp0 = Bm + bl0 * DS;
        if (tid < CLc * DS) bsh[tid] = bp0[tid];
    }

    float Av2[DS];
    {
        const float4* Ap = (const float4*)(A + (size_t)d * DS);
        #pragma unroll
        for (int q = 0; q < 4; ++q) {
            const float4 av = Ap[q];
            Av2[q*4+0] = av.x * LOG2E; Av2[q*4+1] = av.y * LOG2E;
            Av2[q*4+2] = av.z * LOG2E; Av2[q*4+3] = av.w * LOG2E;
        }
    }

    const float* __restrict__ dp = delta + bl0 * DI + d;
    const float* __restrict__ up = u     + bl0 * DI + d;

    float dt[CLc], uu[CLc];
    #pragma unroll
    for (int i = 0; i < CLc; ++i) {
        dt[i] = dp[(size_t)i * DI];          // coalesced 256B/wave
        uu[i] = up[(size_t)i * DI];
    }

    __syncthreads();

    float Bacc[DS];
    #pragma unroll
    for (int n = 0; n < DS; ++n) Bacc[n] = 0.0f;
    float sdt = 0.0f;

    #pragma unroll
    for (int i = 0; i < CLc; ++i) {
        const float du = dt[i] * uu[i];
        sdt += dt[i];
        const float4* bt4 = (const float4*)(bsh + i * DS);   // LDS broadcast
        const float4 b0 = bt4[0], b1 = bt4[1], b2 = bt4[2], b3 = bt4[3];
        const float bv[DS] = {b0.x,b0.y,b0.z,b0.w, b1.x,b1.y,b1.z,b1.w,
                              b2.x,b2.y,b2.z,b2.w, b3.x,b3.y,b3.z,b3.w};
        #pragma unroll
        for (int n = 0; n < DS; ++n) {
            const float a = exp2_fast(dt[i] * Av2[n]);
            Bacc[n] = fmaf(a, Bacc[n], du * bv[n]);
        }
    }

    sdt_out[((size_t)c * BB + b) * DI + d] = sdt;
    float* __restrict__ sp = bsum + (((size_t)c * BB + b) * DI + d) * DS;
    #pragma unroll
    for (int n = 0; n < DS; ++n) sp[n] = Bacc[n];
}

// ---------------------------------------------------------------------------
// Pass 1.5: exclusive scan over chunks per (b,d,n) chain (round-3 proven).
// ---------------------------------------------------------------------------
template <int NCc>
__global__ __launch_bounds__(TPB) void ss_scan(
    const float* __restrict__ A,
    const float* __restrict__ sdt_in, const float* __restrict__ bsum,
    float* __restrict__ xin)
{
    const int gid = blockIdx.x * TPB + threadIdx.x;   // (b*DI+d)*DS+n
    const int bd  = gid >> 4;
    const int d   = bd % DI;
    const int n   = gid & 15;
    const float Av2 = A[d * DS + n] * LOG2E;

    const size_t cstr = (size_t)BB * DI * DS;
    const size_t sstr = (size_t)BB * DI;

    float x = 0.0f;
    #pragma unroll 8
    for (int c = 0; c < NCc; ++c) {
        xin[(size_t)c * cstr + gid] = x;               // state BEFORE chunk c
        const float a = exp2_fast(Av2 * sdt_in[(size_t)c * sstr + bd]);
        x = fmaf(a, x, bsum[(size_t)c * cstr + gid]);
    }
}

// ---------------------------------------------------------------------------
// Pass 2: thread <-> (b, d, chunk); B and C tiles staged via LDS; load
// incoming state, re-run chunk, reduce over n in registers, write y.
// ---------------------------------------------------------------------------
template <int NCc>
__global__ __launch_bounds__(TPB) void ss2(
    const float* __restrict__ u, const float* __restrict__ delta,
    const float* __restrict__ A, const float* __restrict__ Bm,
    const float* __restrict__ Cm, const float* __restrict__ Dv,
    const float* __restrict__ xin, float* __restrict__ y)
{
    constexpr int CLc = LL / NCc;
    __shared__ float bsh[CLc * DS];          // 1 KB
    __shared__ float csh[CLc * DS];          // 1 KB

    const int tid = threadIdx.x;
    const int d = blockIdx.x * TPB + tid;
    const int c = blockIdx.y;
    const int b = blockIdx.z;

    const size_t bl0 = (size_t)b * LL + (size_t)c * CLc;

    // Stage B and C tiles (one coalesced load each).
    {
        const float* __restrict__ bp0 = Bm + bl0 * DS;
        const float* __restrict__ cp0 = Cm + bl0 * DS;
        if (tid < CLc * DS) {
            bsh[tid] = bp0[tid];
            csh[tid] = cp0[tid];
        }
    }

    float Av2[DS];
    {
        const float4* Ap = (const float4*)(A + (size_t)d * DS);
        #pragma unroll
        for (int q = 0; q < 4; ++q) {
            const float4 av = Ap[q];
            Av2[q*4+0] = av.x * LOG2E; Av2[q*4+1] = av.y * LOG2E;
            Av2[q*4+2] = av.z * LOG2E; Av2[q*4+3] = av.w * LOG2E;
        }
    }

    float x[DS];
    {
        const float* __restrict__ xp = xin + (((size_t)c * BB + b) * DI + d) * DS;
        #pragma unroll
        for (int n = 0; n < DS; ++n) x[n] = xp[n];
    }

    const float Dd = Dv[d];

    const float* __restrict__ dp = delta + bl0 * DI + d;
    const float* __restrict__ up = u     + bl0 * DI + d;
    float* __restrict__ yp       = y     + bl0 * DI + d;

    float dt[CLc], uu[CLc];
    #pragma unroll
    for (int i = 0; i < CLc; ++i) {
        dt[i] = dp[(size_t)i * DI];
        uu[i] = up[(size_t)i * DI];
    }

    __syncthreads();

    #pragma unroll
    for (int i = 0; i < CLc; ++i) {
        const float du = dt[i] * uu[i];
        const float4* bt4 = (const float4*)(bsh + i * DS);   // LDS broadcast
        const float4* ct4 = (const float4*)(csh + i * DS);
        const float4 b0 = bt4[0], b1 = bt4[1], b2 = bt4[2], b3 = bt4[3];
        const float4 c0 = ct4[0], c1 = ct4[1], c2 = ct4[2], c3 = ct4[3];
        const float bv[DS] = {b0.x,b0.y,b0.z,b0.w, b1.x,b1.y,b1.z,b1.w,
                              b2.x,b2.y,b2.z,b2.w, b3.x,b3.y,b3.z,b3.w};
        const float cv[DS] = {c0.x,c0.y,c0.z,c0.w, c1.x,c1.y,c1.z,c1.w,
                              c2.x,c2.y,c2.z,c2.w, c3.x,c3.y,c3.z,c3.w};
        float y0 = 0.0f, y1 = 0.0f;
        #pragma unroll
        for (int n = 0; n < DS; ++n) {
            const float a = exp2_fast(dt[i] * Av2[n]);
            x[n] = fmaf(a, x[n], du * bv[n]);
            if (n & 1) y1 = fmaf(x[n], cv[n], y1);
            else       y0 = fmaf(x[n], cv[n], y0);
        }
        yp[(size_t)i * DI] = fmaf(uu[i], Dd, y0 + y1);
    }
}

// Fallback: streaming serial scan (no workspace needed)
__global__ __launch_bounds__(TPB) void ss_serial(
    const float* __restrict__ u, const float* __restrict__ delta,
    const float* __restrict__ A, const float* __restrict__ Bm,
    const float* __restrict__ Cm, const float* __restrict__ Dv,
    float* __restrict__ y)
{
    const int d = blockIdx.x * TPB + threadIdx.x;
    const int b = blockIdx.z;

    float Av2[DS];
    #pragma unroll
    for (int n = 0; n < DS; ++n) Av2[n] = A[d * DS + n] * LOG2E;

    float x[DS];
    #pragma unroll
    for (int n = 0; n < DS; ++n) x[n] = 0.0f;

    const float Dd = Dv[d];
    const size_t bl0 = (size_t)b * LL;
    const float* __restrict__ dp = delta + bl0 * DI + d;
    const float* __restrict__ up = u     + bl0 * DI + d;
    const float* __restrict__ bp = Bm    + bl0 * DS;
    const float* __restrict__ cp = Cm    + bl0 * DS;
    float* __restrict__ yp       = y     + bl0 * DI + d;

    for (int t = 0; t < LL; ++t) {
        const float dtv = dp[(size_t)t * DI];
        const float uuv = up[(size_t)t * DI];
        const float du = dtv * uuv;
        const float* __restrict__ bt = bp + t * DS;
        const float* __restrict__ ct = cp + t * DS;
        float y0 = 0.0f, y1 = 0.0f;
        #pragma unroll
        for (int n = 0; n < DS; ++n) {
            const float a = exp2_fast(dtv * Av2[n]);
            x[n] = fmaf(a, x[n], du * bt[n]);
            if (n & 1) y1 = fmaf(x[n], ct[n], y1);
            else       y0 = fmaf(x[n], ct[n], y0);
        }
        yp[(size_t)t * DI] = fmaf(uuv, Dd, y0 + y1);
    }
}

template <int NCc>
static void launch_chunked(const float* u, const float* delta, const float* A,
                           const float* Bm, const float* Cm, const float* Dv,
                           float* y, void* d_ws, hipStream_t stream) {
    const size_t sdt_bytes  = (size_t)NCc * BB * DI * sizeof(float);
    const size_t bsum_bytes = (size_t)NCc * BB * DI * DS * sizeof(float);

    float* sdt  = (float*)d_ws;
    float* bsum = (float*)((char*)d_ws + sdt_bytes);
    float* xin  = (float*)((char*)d_ws + sdt_bytes + bsum_bytes);

    dim3 grid1(DI / TPB, NCc, BB);
    ss1<NCc><<<grid1, TPB, 0, stream>>>(u, delta, A, Bm, sdt, bsum);

    dim3 gridS((BB * DI * DS) / TPB, 1, 1);
    ss_scan<NCc><<<gridS, TPB, 0, stream>>>(A, sdt, bsum, xin);

    ss2<NCc><<<grid1, TPB, 0, stream>>>(u, delta, A, Bm, Cm, Dv, xin, y);
}

extern "C" void kernel_launch(void* const* d_in, const int* in_sizes, int n_in,
                              void* d_out, int out_size, void* d_ws, size_t ws_size,
                              hipStream_t stream) {
    const float* u     = (const float*)d_in[0];
    const float* delta = (const float*)d_in[1];
    const float* A     = (const float*)d_in[2];
    const float* Bm    = (const float*)d_in[3];
    const float* Cm    = (const float*)d_in[4];
    const float* Dv    = (const float*)d_in[5];
    float* y = (float*)d_out;

    auto need = [](int nc) {
        return (size_t)nc * BB * DI * sizeof(float) +            // sdt
               2 * (size_t)nc * BB * DI * DS * sizeof(float);    // bsum + xin
    };

    if (ws_size >= need(64)) {
        launch_chunked<64>(u, delta, A, Bm, Cm, Dv, y, d_ws, stream);
    } else {
        dim3 grid(DI / TPB, 1, BB);
        ss_serial<<<grid, TPB, 0, stream>>>(u, delta, A, Bm, Cm, Dv, y);
    }
}